// Round 10
// baseline (42.147 us; speedup 1.0000x reference)
//
#include <hip/hip_runtime.h>

#define NBOX 8192
#define NBLK 32
#define BTF 384
#define MAXDET 100
#define SCORE_T 0.05f
#define NMS_T 0.5f
#define CAP 1024
#define CAPM 384
#define NWMAX 6
#define KTGT 128
#define TOPBIN_T 0.99609375f   // 255/256: top value-uniform bin

typedef unsigned long long u64;

__device__ __forceinline__ float rl_f(float v, int j) {
    return __int_as_float(__builtin_amdgcn_readlane(__float_as_int(v), j));
}

__device__ __forceinline__ float iou_fn(float x1, float y1, float x2, float y2, float area,
                                        float bx1, float by1, float bx2, float by2, float barea) {
    float iw = fminf(x2, bx2) - fmaxf(x1, bx1);
    float ih = fminf(y2, by2) - fmaxf(y1, by1);
    iw = fmaxf(iw, 0.0f);
    ih = fmaxf(ih, 0.0f);
    float inter = iw * ih;
    return inter / fmaxf(area + barea - inter, 1e-8f);
}

__device__ __forceinline__ void bins_of(unsigned k, int& b1, int& b2) {
    float s = __uint_as_float(k & 0x7FFFFFFFu);
    b1 = (int)(s * 256.0f); if (b1 > 255) b1 = 255;
    b2 = (int)(s * 65536.0f) & 255;
}

__global__ __launch_bounds__(BTF) void fused_kernel(
    const float* __restrict__ boxes, const float* __restrict__ dims,
    const float* __restrict__ cls, unsigned* __restrict__ cntG,
    unsigned* __restrict__ doneG, u64* __restrict__ kidxG,
    float* __restrict__ out) {
    // ---- shared (fast path) ----
    __shared__ u64 s_sel[CAP];            // 8KB  (both paths)
    __shared__ float4 s_cb[CAP];          // 16KB (both paths)
    __shared__ u64 s_gt[NWMAX][CAPM];     // 18KB
    __shared__ u64 s_sg[NWMAX][CAPM];     // 18KB
    __shared__ u64 s_K[NWMAX], s_U[NWMAX];
    // ---- shared (fallback path) ----
    __shared__ unsigned s_keyS[NBOX];     // 32KB
    __shared__ unsigned s_hist[256];
    __shared__ u64 s_srt[CAP];            // 8KB
    __shared__ unsigned short s_srtpos[CAP];
    __shared__ float4 s_bb[128];
    __shared__ float s_bar[128];
    __shared__ float4 s_kb[MAXDET];
    __shared__ float s_karea[MAXDET], s_kscore[MAXDET];
    __shared__ int s_ksel[MAXDET];
    __shared__ int s_kc, s_cnt, s_B1, s_B2, s_state, s_refKrem;
    __shared__ u64 s_alive0;
    __shared__ int s_lcnt, s_base, s_last;

    const int tid = threadIdx.x;
    const int lane = tid & 63;
    const int w = tid >> 6;
    const int blk = blockIdx.x;

    // ================= Phase A (all blocks): chip-parallel score + push =================
    if (tid == 0) s_lcnt = 0;
    __syncthreads();
    u64 myv = 0ull;
    int lpos = -1;
    if (tid < 256) {
        const int i = blk * 256 + tid;
        const float4 c0 = *reinterpret_cast<const float4*>(cls + i * 8);
        const float4 c1 = *reinterpret_cast<const float4*>(cls + i * 8 + 4);
        float m0 = fmaxf(c0.x, c1.x), m1 = fmaxf(c0.y, c1.y);
        float m2 = fmaxf(c0.z, c1.z), m3 = fmaxf(c0.w, c1.w);
        float s = fmaxf(fmaxf(m0, m1), fmaxf(m2, m3));
        if (s > SCORE_T && s >= TOPBIN_T) {
            unsigned u = __float_as_uint(s);
            unsigned key = (u >> 31) ? ~u : (u | 0x80000000u);
            myv = (((u64)key) << 13) | (unsigned)(NBOX - 1 - i);
            lpos = atomicAdd(&s_lcnt, 1);
        }
    }
    __syncthreads();
    if (tid == 0) s_base = (int)atomicAdd(cntG, (unsigned)s_lcnt);
    __syncthreads();
    if (lpos >= 0) {
        int g = s_base + lpos;
        if (g < CAPM) atomicExch(&kidxG[g], myv);
    }
    __threadfence();
    __syncthreads();
    if (tid == 0) s_last = (atomicAdd(doneG, 1u) == (unsigned)(NBLK - 1)) ? 1 : 0;
    __syncthreads();
    if (!s_last) return;
    __threadfence();

    // ================= FINISHER (last block only) =================
    const int cnt = (int)atomicAdd(cntG, 0u);

    if (cnt > 0 && cnt <= CAPM) {
        // ---- gather candidate list (device-coherent RMW reads) ----
        for (int t = tid; t < cnt; t += BTF) {
            u64 v = atomicAdd(&kidxG[t], 0ull);
            s_sel[t] = v;
            int idx = NBOX - 1 - (int)(v & 8191ull);
            s_cb[t] = *reinterpret_cast<const float4*>(boxes + idx * 12);
        }
        __syncthreads();
        const int NW = (cnt + 63) >> 6;
        // ---- all-pairs gt/suppress masks, word-major ----
        const int tot = NW * cnt;
        for (int p = tid; p < tot; p += BTF) {
            int q = p / cnt;
            int t = p - q * cnt;
            u64 selt = s_sel[t];
            float4 bt = s_cb[t];
            float x1 = bt.x, y1 = bt.y, x2 = bt.z, y2 = bt.w;
            float area = (x2 - x1) * (y2 - y1);
            int jbase = q << 6;
            int jmax = cnt - jbase; if (jmax > 64) jmax = 64;
            u64 g = 0ull, sg = 0ull;
            for (int jj = 0; jj < jmax; ++jj) {
                int jdx = jbase + jj;
                u64 selj = s_sel[jdx];
                float4 bj = s_cb[jdx];
                float barea = (bj.z - bj.x) * (bj.w - bj.y);
                float iou = iou_fn(x1, y1, x2, y2, area, bj.x, bj.y, bj.z, bj.w, barea);
                if (selj > selt) {
                    u64 bit = 1ull << jj;
                    g |= bit;
                    if (iou > NMS_T) sg |= bit;
                }
            }
            s_gt[q][t] = g;
            s_sg[q][t] = sg;
        }
        if (tid < NWMAX) {
            int base = tid << 6;
            u64 uw = (cnt <= base) ? 0ull
                   : ((cnt - base >= 64) ? ~0ull : ((1ull << (cnt - base)) - 1ull));
            s_U[tid] = uw;
            s_K[tid] = 0ull;
        }
        __syncthreads();
        // ---- fixpoint: exact greedy ----
        const int t = tid;
        const bool have = t < cnt;
        for (int it = 0; it < CAPM; ++it) {
            bool undec = have && ((s_U[t >> 6] >> (t & 63)) & 1ull);
            u64 deadm = 0ull, blkm = 0ull;
            if (undec) {
                for (int q = 0; q < NW; ++q) {
                    u64 sg = s_sg[q][t];
                    deadm |= sg & s_K[q];
                    blkm  |= sg & s_U[q];
                }
            }
            bool toDead = undec && (deadm != 0ull);
            bool toKept = undec && (deadm == 0ull) && (blkm == 0ull);
            u64 dW = __ballot(toDead);
            u64 kW = __ballot(toKept);
            if (lane == 0 && w < NW) {
                s_K[w] |= kW;
                s_U[w] &= ~(kW | dW);
            }
            __syncthreads();
            u64 anyU = 0ull;
            for (int q = 0; q < NW; ++q) anyU |= s_U[q];
            if (anyU == 0ull) break;
            __syncthreads();
        }
        int kcnt = 0;
        for (int q = 0; q < NW; ++q) kcnt += (int)__popcll(s_K[q]);
        if (kcnt >= MAXDET) {
            // ---- fast output: kept & rank<100 writes slot=rank ----
            float* ob = out;
            float* od = out + MAXDET * 12;
            float* os = out + MAXDET * 15;
            float* ol = out + MAXDET * 16;
            float* oo = out + MAXDET * 17;
            if (have && ((s_K[t >> 6] >> (t & 63)) & 1ull)) {
                int rank = 0;
                for (int q = 0; q < NW; ++q) rank += (int)__popcll(s_gt[q][t] & s_K[q]);
                if (rank < MAXDET) {
                    u64 v = s_sel[t];
                    int idx = NBOX - 1 - (int)(v & 8191ull);
                    float sscore = __uint_as_float(((unsigned)(v >> 13)) & 0x7FFFFFFFu);
                    float4* obr = reinterpret_cast<float4*>(ob + rank * 12);
                    const float4* br = reinterpret_cast<const float4*>(boxes + idx * 12);
                    obr[0] = s_cb[t];
                    obr[1] = br[1];
                    obr[2] = br[2];
                    od[rank * 3 + 0] = dims[idx * 3 + 0];
                    od[rank * 3 + 1] = dims[idx * 3 + 1];
                    od[rank * 3 + 2] = dims[idx * 3 + 2];
                    os[rank] = sscore;
                    ol[rank] = 0.0f;
                    const float4 c0 = *reinterpret_cast<const float4*>(cls + idx * 8);
                    const float4 c1 = *reinterpret_cast<const float4*>(cls + idx * 8 + 4);
                    float m0 = fmaxf(c0.x, c1.x), m1 = fmaxf(c0.y, c1.y);
                    float m2 = fmaxf(c0.z, c1.z), m3 = fmaxf(c0.w, c1.w);
                    int o = 0; float best = m0;
                    if (m1 > best) { best = m1; o = 1; }
                    if (m2 > best) { best = m2; o = 2; }
                    if (m3 > best) { best = m3; o = 3; }
                    oo[rank] = (float)o;
                }
            }
            return;
        }
        // else fall through to full solver
    }

    // ================= FALLBACK (adversarial only): complete banded solver =================
    {
        auto rank_scatter = [&](int sc) {
            for (int t = tid; t < sc; t += BTF) {
                u64 mine = s_sel[t];
                int bidx = NBOX - 1 - (int)(mine & 8191ull);
                float4 pb = *reinterpret_cast<const float4*>(boxes + bidx * 12);
                int rank = 0;
                int j = 0;
                for (; j + 8 <= sc; j += 8) {
                    u64 a0 = s_sel[j + 0], a1 = s_sel[j + 1], a2 = s_sel[j + 2], a3 = s_sel[j + 3];
                    u64 a4 = s_sel[j + 4], a5 = s_sel[j + 5], a6 = s_sel[j + 6], a7 = s_sel[j + 7];
                    rank += (int)(a0 > mine) + (int)(a1 > mine) + (int)(a2 > mine) + (int)(a3 > mine)
                          + (int)(a4 > mine) + (int)(a5 > mine) + (int)(a6 > mine) + (int)(a7 > mine);
                }
                for (; j < sc; ++j) rank += (s_sel[j] > mine) ? 1 : 0;
                s_srt[rank] = mine;
                s_srtpos[rank] = (unsigned short)t;
                s_cb[t] = pb;
            }
        };

        auto nms_groups = [&](int scN) {
            for (int base = 0; base < scN && s_kc < MAXDET; base += 128) {
                const int kc0 = s_kc;
                float x1 = 0.f, y1 = 0.f, x2 = 0.f, y2 = 0.f, area = 0.f, sscore = 0.f;
                int sidx = 0; bool have2 = false;
                if (w < 2) {
                    int p = base + w * 64 + lane;
                    have2 = p < scN;
                    u64 v = have2 ? s_srt[p] : 0ull;
                    int cp = have2 ? (int)s_srtpos[p] : 0;
                    sidx = NBOX - 1 - (int)(v & 8191ull);
                    sscore = __uint_as_float(((unsigned)(v >> 13)) & 0x7FFFFFFFu);
                    float4 b = s_cb[cp];
                    if (have2) { x1 = b.x; y1 = b.y; x2 = b.z; y2 = b.w; area = (x2 - x1) * (y2 - y1); }
                    int sl = w * 64 + lane;
                    s_bb[sl] = make_float4(x1, y1, x2, y2); s_bar[sl] = area;
                }
                __syncthreads();
                if (w == 0) {
                    bool cand = have2;
                    for (int k = 0; k < kc0; ++k) {
                        float4 kb = s_kb[k];
                        float iou = iou_fn(x1, y1, x2, y2, area, kb.x, kb.y, kb.z, kb.w, s_karea[k]);
                        cand = cand && !(iou > NMS_T);
                    }
                    u64 m = 0ull;
#pragma unroll 8
                    for (int j = 0; j < 64; ++j) {
                        float iou = iou_fn(x1, y1, x2, y2, area,
                                           rl_f(x1, j), rl_f(y1, j), rl_f(x2, j), rl_f(y2, j), rl_f(area, j));
                        if ((iou > NMS_T) && (j < lane)) m |= (1ull << j);
                    }
                    u64 alive = __ballot(cand);
                    u64 conf = __ballot((m & alive) != 0ull) & alive;
                    while (conf) {
                        int i = (int)__builtin_ctzll(conf);
                        bool deadI = (lane == i) && ((m & alive) != 0ull);
                        u64 d = __ballot(deadI);
                        alive &= ~d; conf &= ~(d | (1ull << i));
                    }
                    int rank = (int)__popcll(alive & ((1ull << lane) - 1ull));
                    int slot = kc0 + rank;
                    if (((alive >> lane) & 1ull) && slot < MAXDET) {
                        s_kb[slot] = make_float4(x1, y1, x2, y2);
                        s_karea[slot] = area; s_kscore[slot] = sscore; s_ksel[slot] = sidx;
                    }
                    if (lane == 0) s_alive0 = alive;
                }
                u64 m_low = 0ull, m_high = 0ull;
                bool cand1 = have2;
                if (w == 1) {
                    for (int k = 0; k < kc0; ++k) {
                        float4 kb = s_kb[k];
                        float iou = iou_fn(x1, y1, x2, y2, area, kb.x, kb.y, kb.z, kb.w, s_karea[k]);
                        cand1 = cand1 && !(iou > NMS_T);
                    }
#pragma unroll 8
                    for (int j = 0; j < 64; ++j) {
                        float4 bb = s_bb[j];
                        float iou = iou_fn(x1, y1, x2, y2, area, bb.x, bb.y, bb.z, bb.w, s_bar[j]);
                        if (iou > NMS_T) m_low |= (1ull << j);
                    }
#pragma unroll 8
                    for (int j = 0; j < 64; ++j) {
                        float iou = iou_fn(x1, y1, x2, y2, area,
                                           rl_f(x1, j), rl_f(y1, j), rl_f(x2, j), rl_f(y2, j), rl_f(area, j));
                        if ((iou > NMS_T) && (j < lane)) m_high |= (1ull << j);
                    }
                }
                __syncthreads();
                if (w == 1) {
                    u64 alive0 = s_alive0;
                    int popc0 = (int)__popcll(alive0);
                    bool cand = cand1 && ((m_low & alive0) == 0ull);
                    u64 alive = __ballot(cand);
                    u64 conf = __ballot((m_high & alive) != 0ull) & alive;
                    while (conf) {
                        int i = (int)__builtin_ctzll(conf);
                        bool deadI = (lane == i) && ((m_high & alive) != 0ull);
                        u64 d = __ballot(deadI);
                        alive &= ~d; conf &= ~(d | (1ull << i));
                    }
                    int rank = (int)__popcll(alive & ((1ull << lane) - 1ull));
                    int slot = kc0 + popc0 + rank;
                    if (((alive >> lane) & 1ull) && slot < MAXDET) {
                        s_kb[slot] = make_float4(x1, y1, x2, y2);
                        s_karea[slot] = area; s_kscore[slot] = sscore; s_ksel[slot] = sidx;
                    }
                    if (lane == 0) {
                        int nk = kc0 + popc0 + (int)__popcll(alive);
                        s_kc = nk > MAXDET ? MAXDET : nk;
                    }
                }
                __syncthreads();
            }
        };

        // recompute all keys
        for (int i = tid; i < NBOX; i += BTF) {
            const float4 c0 = *reinterpret_cast<const float4*>(cls + i * 8);
            const float4 c1 = *reinterpret_cast<const float4*>(cls + i * 8 + 4);
            float s = fmaxf(fmaxf(fmaxf(c0.x, c1.x), fmaxf(c0.y, c1.y)),
                            fmaxf(fmaxf(c0.z, c1.z), fmaxf(c0.w, c1.w)));
            unsigned u = __float_as_uint(s);
            unsigned key = (u >> 31) ? ~u : (u | 0x80000000u);
            s_keyS[i] = (s > SCORE_T) ? key : 0u;
        }
        if (tid == 0) { s_kc = 0; s_cnt = 0; }
        if (tid < 256) s_hist[tid] = 0u;
        __syncthreads();

        int U1 = 256, U2 = 0;
        for (int i = tid; i < NBOX; i += BTF) {
            unsigned k = s_keyS[i];
            if (k) { int b1, b2; bins_of(k, b1, b2); atomicAdd(&s_hist[b1], 1u); }
        }
        while (true) {
            __syncthreads();
            if (w == 0) {
                unsigned c0 = s_hist[lane * 4 + 0], c1s = s_hist[lane * 4 + 1];
                unsigned c2 = s_hist[lane * 4 + 2], c3 = s_hist[lane * 4 + 3];
                unsigned t3 = c3, t2 = c2 + t3, t1 = c1s + t2, t0 = c0 + t1;
                unsigned acc = t0;
#pragma unroll
                for (int d = 1; d < 64; d <<= 1) {
                    unsigned o = __shfl_down(acc, d);
                    if (lane + d < 64) acc += o;
                }
                unsigned excl = acc - t0;
                unsigned totalRem = __shfl(acc, 0);
                if (lane == 0) s_state = (totalRem == 0u) ? 2 : 0;
                if (totalRem != 0u) {
                    unsigned Kt = totalRem < (unsigned)KTGT ? totalRem : (unsigned)KTGT;
                    unsigned incq[4] = { excl + t0, excl + t1, excl + t2, excl + t3 };
                    unsigned abvq[4] = { excl + t1, excl + t2, excl + t3, excl };
#pragma unroll
                    for (int q = 0; q < 4; ++q) {
                        if (incq[q] >= Kt && abvq[q] < Kt) {
                            s_B1 = lane * 4 + q; s_B2 = 0;
                            if (incq[q] > CAP) { s_state = 1; s_refKrem = (int)(Kt - abvq[q]); }
                        }
                    }
                }
            }
            __syncthreads();
            const int st = s_state;
            if (st == 2) break;
            const int B1 = s_B1;
            if (st == 1) {
                if (tid < 256) s_hist[tid] = 0u;
                __syncthreads();
                for (int i = tid; i < NBOX; i += BTF) {
                    unsigned k = s_keyS[i];
                    if (k) {
                        int b1, b2; bins_of(k, b1, b2);
                        if ((b1 < U1 || (b1 == U1 && b2 < U2)) && b1 == B1)
                            atomicAdd(&s_hist[b2], 1u);
                    }
                }
                __syncthreads();
                if (w == 0) {
                    unsigned c0 = s_hist[lane * 4 + 0], c1s = s_hist[lane * 4 + 1];
                    unsigned c2 = s_hist[lane * 4 + 2], c3 = s_hist[lane * 4 + 3];
                    unsigned t3 = c3, t2 = c2 + t3, t1 = c1s + t2, t0 = c0 + t1;
                    unsigned acc = t0;
#pragma unroll
                    for (int d = 1; d < 64; d <<= 1) {
                        unsigned o = __shfl_down(acc, d);
                        if (lane + d < 64) acc += o;
                    }
                    unsigned excl = acc - t0;
                    unsigned Krem = (unsigned)s_refKrem;
                    unsigned incq[4] = { excl + t0, excl + t1, excl + t2, excl + t3 };
                    unsigned abvq[4] = { excl + t1, excl + t2, excl + t3, excl };
#pragma unroll
                    for (int q = 0; q < 4; ++q)
                        if (incq[q] >= Krem && abvq[q] < Krem) s_B2 = lane * 4 + q;
                }
                __syncthreads();
            }
            const int B2 = s_B2;
            for (int i = tid; i < NBOX; i += BTF) {
                unsigned k = s_keyS[i];
                if (k) {
                    int b1, b2; bins_of(k, b1, b2);
                    bool inr = (b1 < U1) || (b1 == U1 && b2 < U2);
                    bool sel = inr && ((b1 > B1) || (b1 == B1 && b2 >= B2));
                    if (sel) {
                        int pos = atomicAdd(&s_cnt, 1);
                        if (pos < CAP)
                            s_sel[pos] = (((u64)k) << 13) | (unsigned)(NBOX - 1 - i);
                    }
                }
            }
            __syncthreads();
            const int sc2 = s_cnt < CAP ? s_cnt : CAP;
            rank_scatter(sc2);
            __syncthreads();
            nms_groups(sc2);
            if (s_kc >= MAXDET) break;
            U1 = B1; U2 = B2;
            if (tid < 256) s_hist[tid] = 0u;
            if (tid == 0) s_cnt = 0;
            __syncthreads();
            for (int i = tid; i < NBOX; i += BTF) {
                unsigned k = s_keyS[i];
                if (k) {
                    int b1, b2; bins_of(k, b1, b2);
                    if (b1 < U1 || (b1 == U1 && b2 < U2)) atomicAdd(&s_hist[b1], 1u);
                }
            }
        }
        __syncthreads();

        if (tid < MAXDET) {
            const int kc = s_kc;
            float* ob = out;
            float* od = out + MAXDET * 12;
            float* os = out + MAXDET * 15;
            float* ol = out + MAXDET * 16;
            float* oo = out + MAXDET * 17;
            float4* obr = reinterpret_cast<float4*>(ob + tid * 12);
            if (tid < kc) {
                int sel = s_ksel[tid];
                const float4* br = reinterpret_cast<const float4*>(boxes + sel * 12);
                obr[0] = br[0]; obr[1] = br[1]; obr[2] = br[2];
                od[tid * 3 + 0] = dims[sel * 3 + 0];
                od[tid * 3 + 1] = dims[sel * 3 + 1];
                od[tid * 3 + 2] = dims[sel * 3 + 2];
                os[tid] = s_kscore[tid];
                ol[tid] = 0.0f;
                const float4 c0 = *reinterpret_cast<const float4*>(cls + sel * 8);
                const float4 c1 = *reinterpret_cast<const float4*>(cls + sel * 8 + 4);
                float m0 = fmaxf(c0.x, c1.x), m1 = fmaxf(c0.y, c1.y);
                float m2 = fmaxf(c0.z, c1.z), m3 = fmaxf(c0.w, c1.w);
                int o = 0; float best = m0;
                if (m1 > best) { best = m1; o = 1; }
                if (m2 > best) { best = m2; o = 2; }
                if (m3 > best) { best = m3; o = 3; }
                oo[tid] = (float)o;
            } else {
                const float4 neg1 = make_float4(-1.f, -1.f, -1.f, -1.f);
                obr[0] = neg1; obr[1] = neg1; obr[2] = neg1;
                od[tid * 3 + 0] = -1.0f; od[tid * 3 + 1] = -1.0f; od[tid * 3 + 2] = -1.0f;
                os[tid] = -1.0f; ol[tid] = -1.0f; oo[tid] = -1.0f;
            }
        }
    }
}

extern "C" void kernel_launch(void* const* d_in, const int* in_sizes, int n_in,
                              void* d_out, int out_size, void* d_ws, size_t ws_size,
                              hipStream_t stream) {
    const float* boxes = (const float*)d_in[0];
    const float* dims  = (const float*)d_in[1];
    const float* cls   = (const float*)d_in[2];
    float* out = (float*)d_out;
    unsigned char* ws = (unsigned char*)d_ws;
    unsigned* cnt  = (unsigned*)(ws);        // [0] cnt, [4] done
    unsigned* done = (unsigned*)(ws + 4);
    u64* kidx      = (u64*)(ws + 1024);
    (void)in_sizes; (void)n_in; (void)out_size; (void)ws_size;
    hipMemsetAsync(ws, 0, 8, stream);
    fused_kernel<<<NBLK, BTF, 0, stream>>>(boxes, dims, cls, cnt, done, kidx, out);
}

// Round 11
// 26.469 us; speedup vs baseline: 1.5923x; 1.5923x over previous
//
#include <hip/hip_runtime.h>

#define NBOX 8192
#define BT 1024
#define MAXDET 100
#define SCORE_T 0.05f
#define NMS_T 0.5f
#define CAP 1024
#define CAPM 384
#define KTGT 128
#define TOPBIN_T 0.99609375f   // 255/256: top value-uniform bin

typedef unsigned long long u64;

__device__ __forceinline__ float rl_f(float v, int j) {
    return __int_as_float(__builtin_amdgcn_readlane(__float_as_int(v), j));
}

__device__ __forceinline__ float iou_fn(float x1, float y1, float x2, float y2, float area,
                                        float bx1, float by1, float bx2, float by2, float barea) {
    float iw = fminf(x2, bx2) - fmaxf(x1, bx1);
    float ih = fminf(y2, by2) - fmaxf(y1, by1);
    iw = fmaxf(iw, 0.0f);
    ih = fmaxf(ih, 0.0f);
    float inter = iw * ih;
    return inter / fmaxf(area + barea - inter, 1e-8f);
}

__device__ __forceinline__ void bins_of(unsigned k, int& b1, int& b2) {
    float s = __uint_as_float(k & 0x7FFFFFFFu);
    b1 = (int)(s * 256.0f); if (b1 > 255) b1 = 255;
    b2 = (int)(s * 65536.0f) & 255;
}

__global__ __launch_bounds__(BT) void filterdet_kernel(
    const float* __restrict__ boxes, const float* __restrict__ dims,
    const float* __restrict__ cls, float* __restrict__ out) {
    __shared__ unsigned s_key[NBOX];              // 32KB (fallback)
    __shared__ unsigned s_hist[256];
    __shared__ u64 s_sel[CAP];                    // 8KB
    __shared__ u64 s_srt[CAP];                    // 8KB
    __shared__ unsigned short s_srtpos[CAP];      // 2KB
    __shared__ float4 s_cb[CAP];                  // 16KB (box row0)
    __shared__ float4 s_pay[CAPM][3];             // 18KB (kp0,kp1,dims) fast path
    __shared__ unsigned char s_orr[CAPM];
    __shared__ int s_rank[CAPM];
    __shared__ float4 s_bb[128];
    __shared__ float s_bar[128];
    __shared__ float4 s_kb[MAXDET];
    __shared__ float s_karea[MAXDET];
    __shared__ u64 s_kv[MAXDET];
    __shared__ unsigned short s_kcp[MAXDET];
    __shared__ int s_kc, s_cnt, s_B1, s_B2, s_state, s_refKrem;
    __shared__ u64 s_alive0;

    const int tid = threadIdx.x;
    const int lane = tid & 63;
    const int wid = tid >> 6;

    // exact greedy NMS over s_srt[0..scN), 2-wave cooperative, groups of 128
    auto nms_groups = [&](int scN, bool hasPay) {
        for (int base = 0; base < scN && s_kc < MAXDET; base += 128) {
            const int kc0 = s_kc;
            float x1 = 0.f, y1 = 0.f, x2 = 0.f, y2 = 0.f, area = 0.f;
            u64 v = 0ull; int cp = 0; bool have = false;
            if (wid < 2) {
                int p = base + wid * 64 + lane;
                have = p < scN;
                v = have ? s_srt[p] : 0ull;
                cp = have ? (int)s_srtpos[p] : 0;
                float4 b = s_cb[cp];
                if (have) { x1 = b.x; y1 = b.y; x2 = b.z; y2 = b.w; area = (x2 - x1) * (y2 - y1); }
                int sl = wid * 64 + lane;
                s_bb[sl] = make_float4(x1, y1, x2, y2); s_bar[sl] = area;
            }
            __syncthreads();
            if (wid == 0) {
                bool cand = have;
                for (int k = 0; k < kc0; ++k) {
                    float4 kb = s_kb[k];
                    float iou = iou_fn(x1, y1, x2, y2, area, kb.x, kb.y, kb.z, kb.w, s_karea[k]);
                    cand = cand && !(iou > NMS_T);
                }
                u64 m = 0ull;
#pragma unroll 8
                for (int j = 0; j < 64; ++j) {
                    float iou = iou_fn(x1, y1, x2, y2, area,
                                       rl_f(x1, j), rl_f(y1, j), rl_f(x2, j), rl_f(y2, j), rl_f(area, j));
                    if ((iou > NMS_T) && (j < lane)) m |= (1ull << j);
                }
                u64 alive = __ballot(cand);
                u64 conf = __ballot((m & alive) != 0ull) & alive;
                while (conf) {
                    int i = (int)__builtin_ctzll(conf);
                    bool deadI = (lane == i) && ((m & alive) != 0ull);
                    u64 d = __ballot(deadI);
                    alive &= ~d; conf &= ~(d | (1ull << i));
                }
                int rank = (int)__popcll(alive & ((1ull << lane) - 1ull));
                int slot = kc0 + rank;
                if (((alive >> lane) & 1ull) && slot < MAXDET) {
                    s_kb[slot] = make_float4(x1, y1, x2, y2);
                    s_karea[slot] = area; s_kv[slot] = v;
                    s_kcp[slot] = hasPay ? (unsigned short)cp : (unsigned short)0xFFFF;
                }
                if (lane == 0) s_alive0 = alive;
            }
            u64 m_low = 0ull, m_high = 0ull;
            bool cand1 = have;
            if (wid == 1) {
                for (int k = 0; k < kc0; ++k) {
                    float4 kb = s_kb[k];
                    float iou = iou_fn(x1, y1, x2, y2, area, kb.x, kb.y, kb.z, kb.w, s_karea[k]);
                    cand1 = cand1 && !(iou > NMS_T);
                }
#pragma unroll 8
                for (int j = 0; j < 64; ++j) {
                    float4 bb = s_bb[j];
                    float iou = iou_fn(x1, y1, x2, y2, area, bb.x, bb.y, bb.z, bb.w, s_bar[j]);
                    if (iou > NMS_T) m_low |= (1ull << j);
                }
#pragma unroll 8
                for (int j = 0; j < 64; ++j) {
                    float iou = iou_fn(x1, y1, x2, y2, area,
                                       rl_f(x1, j), rl_f(y1, j), rl_f(x2, j), rl_f(y2, j), rl_f(area, j));
                    if ((iou > NMS_T) && (j < lane)) m_high |= (1ull << j);
                }
            }
            __syncthreads();
            if (wid == 1) {
                u64 alive0 = s_alive0;
                int popc0 = (int)__popcll(alive0);
                bool cand = cand1 && ((m_low & alive0) == 0ull);
                u64 alive = __ballot(cand);
                u64 conf = __ballot((m_high & alive) != 0ull) & alive;
                while (conf) {
                    int i = (int)__builtin_ctzll(conf);
                    bool deadI = (lane == i) && ((m_high & alive) != 0ull);
                    u64 d = __ballot(deadI);
                    alive &= ~d; conf &= ~(d | (1ull << i));
                }
                int rank = (int)__popcll(alive & ((1ull << lane) - 1ull));
                int slot = kc0 + popc0 + rank;
                if (((alive >> lane) & 1ull) && slot < MAXDET) {
                    s_kb[slot] = make_float4(x1, y1, x2, y2);
                    s_karea[slot] = area; s_kv[slot] = v;
                    s_kcp[slot] = hasPay ? (unsigned short)cp : (unsigned short)0xFFFF;
                }
                if (lane == 0) {
                    int nk = kc0 + popc0 + (int)__popcll(alive);
                    s_kc = nk > MAXDET ? MAXDET : nk;
                }
            }
            __syncthreads();
        }
    };

    // ---- init ----
    if (tid == 0) { s_kc = 0; s_cnt = 0; }
    if (tid < CAPM) s_rank[tid] = 0;
    __syncthreads();

    // ---- P1: keys + wave-aggregated push (orient + payload prefetched) ----
#pragma unroll
    for (int j = 0; j < NBOX / BT; ++j) {
        int i = tid + j * BT;
        const float4 c0 = *reinterpret_cast<const float4*>(cls + i * 8);
        const float4 c1 = *reinterpret_cast<const float4*>(cls + i * 8 + 4);
        float m0 = fmaxf(c0.x, c1.x), m1 = fmaxf(c0.y, c1.y);
        float m2 = fmaxf(c0.z, c1.z), m3 = fmaxf(c0.w, c1.w);
        float s = fmaxf(fmaxf(m0, m1), fmaxf(m2, m3));
        unsigned u = __float_as_uint(s);
        unsigned key = (u >> 31) ? ~u : (u | 0x80000000u);
        key = (s > SCORE_T) ? key : 0u;
        s_key[i] = key;
        bool isc = (key != 0u) && (s >= TOPBIN_T);
        u64 bal = __ballot(isc);
        int nb = (int)__popcll(bal);
        int b = 0;
        if (lane == 0 && nb) b = atomicAdd(&s_cnt, nb);
        b = __shfl(b, 0);
        if (isc) {
            int pos = b + (int)__popcll(bal & ((1ull << lane) - 1ull));
            if (pos < CAPM) {
                int o = 0; float best = m0;
                if (m1 > best) { best = m1; o = 1; }
                if (m2 > best) { best = m2; o = 2; }
                if (m3 > best) { best = m3; o = 3; }
                s_sel[pos] = (((u64)key) << 13) | (unsigned)(NBOX - 1 - i);
                s_orr[pos] = (unsigned char)o;
                const float4* br = reinterpret_cast<const float4*>(boxes + i * 12);
                s_cb[pos] = br[0];
                s_pay[pos][0] = br[1];
                s_pay[pos][1] = br[2];
                s_pay[pos][2] = make_float4(dims[i * 3], dims[i * 3 + 1], dims[i * 3 + 2], 0.f);
            }
        }
    }
    __syncthreads();
    const int cnt0 = s_cnt;
    const bool ovf = cnt0 > CAPM;

    // ---- FAST PATH: 4x-parallel rank-sort + NMS ----
    if (!ovf && cnt0 > 0) {
        const int sc = cnt0;
        const int p = tid & 3;
        const int chunk = (sc + 3) >> 2;
        const int j0 = p * chunk;
        int j1 = j0 + chunk; if (j1 > sc) j1 = sc;
        for (int c = tid >> 2; c < sc; c += 256) {
            u64 mine = s_sel[c];
            int r = 0;
            int j = j0;
            for (; j + 8 <= j1; j += 8) {
                u64 a0 = s_sel[j + 0], a1 = s_sel[j + 1], a2 = s_sel[j + 2], a3 = s_sel[j + 3];
                u64 a4 = s_sel[j + 4], a5 = s_sel[j + 5], a6 = s_sel[j + 6], a7 = s_sel[j + 7];
                r += (int)(a0 > mine) + (int)(a1 > mine) + (int)(a2 > mine) + (int)(a3 > mine)
                   + (int)(a4 > mine) + (int)(a5 > mine) + (int)(a6 > mine) + (int)(a7 > mine);
            }
            for (; j < j1; ++j) r += (s_sel[j] > mine) ? 1 : 0;
            if (r) atomicAdd(&s_rank[c], r);
        }
        __syncthreads();
        if (tid < sc) { int rk = s_rank[tid]; s_srt[rk] = s_sel[tid]; s_srtpos[rk] = (unsigned short)tid; }
        __syncthreads();
        nms_groups(sc, true);
    }

    int U1 = ovf ? 256 : 255;   // exclusive band bound for fallback continuation
    int U2 = 0;

    // ---- FALLBACK (adversarial only): banded selection over all keys ----
    if (s_kc < MAXDET) {
        auto rank_scatter = [&](int sc) {
            if (tid < sc) {
                u64 mine = s_sel[tid];
                int bidx = NBOX - 1 - (int)(mine & 8191ull);
                float4 pb = *reinterpret_cast<const float4*>(boxes + bidx * 12);
                int rank = 0;
                int j = 0;
                for (; j + 8 <= sc; j += 8) {
                    u64 a0 = s_sel[j + 0], a1 = s_sel[j + 1], a2 = s_sel[j + 2], a3 = s_sel[j + 3];
                    u64 a4 = s_sel[j + 4], a5 = s_sel[j + 5], a6 = s_sel[j + 6], a7 = s_sel[j + 7];
                    rank += (int)(a0 > mine) + (int)(a1 > mine) + (int)(a2 > mine) + (int)(a3 > mine)
                          + (int)(a4 > mine) + (int)(a5 > mine) + (int)(a6 > mine) + (int)(a7 > mine);
                }
                for (; j < sc; ++j) rank += (s_sel[j] > mine) ? 1 : 0;
                s_srt[rank] = mine;
                s_srtpos[rank] = (unsigned short)tid;
                s_cb[tid] = pb;
            }
        };

        if (tid < 256) s_hist[tid] = 0u;
        if (tid == 0) s_cnt = 0;
        __syncthreads();
        for (int j = 0; j < NBOX / BT; ++j) {
            unsigned k = s_key[tid + j * BT];
            if (k) {
                int b1, b2; bins_of(k, b1, b2);
                if (b1 < U1 || (b1 == U1 && b2 < U2)) atomicAdd(&s_hist[b1], 1u);
            }
        }
        while (true) {
            __syncthreads();
            if (wid == 0) {
                unsigned c0 = s_hist[lane * 4 + 0], c1s = s_hist[lane * 4 + 1];
                unsigned c2 = s_hist[lane * 4 + 2], c3 = s_hist[lane * 4 + 3];
                unsigned t3 = c3, t2 = c2 + t3, t1 = c1s + t2, t0 = c0 + t1;
                unsigned acc = t0;
#pragma unroll
                for (int d = 1; d < 64; d <<= 1) {
                    unsigned o = __shfl_down(acc, d);
                    if (lane + d < 64) acc += o;
                }
                unsigned excl = acc - t0;
                unsigned totalRem = __shfl(acc, 0);
                if (lane == 0) s_state = (totalRem == 0u) ? 2 : 0;
                if (totalRem != 0u) {
                    unsigned Kt = totalRem < (unsigned)KTGT ? totalRem : (unsigned)KTGT;
                    unsigned incq[4] = { excl + t0, excl + t1, excl + t2, excl + t3 };
                    unsigned abvq[4] = { excl + t1, excl + t2, excl + t3, excl };
#pragma unroll
                    for (int q = 0; q < 4; ++q) {
                        if (incq[q] >= Kt && abvq[q] < Kt) {
                            s_B1 = lane * 4 + q; s_B2 = 0;
                            if (incq[q] > CAP) { s_state = 1; s_refKrem = (int)(Kt - abvq[q]); }
                        }
                    }
                }
            }
            __syncthreads();
            const int st = s_state;
            if (st == 2) break;
            const int B1 = s_B1;
            if (st == 1) {
                if (tid < 256) s_hist[tid] = 0u;
                __syncthreads();
                for (int j = 0; j < NBOX / BT; ++j) {
                    unsigned k = s_key[tid + j * BT];
                    if (k) {
                        int b1, b2; bins_of(k, b1, b2);
                        if ((b1 < U1 || (b1 == U1 && b2 < U2)) && b1 == B1)
                            atomicAdd(&s_hist[b2], 1u);
                    }
                }
                __syncthreads();
                if (wid == 0) {
                    unsigned c0 = s_hist[lane * 4 + 0], c1s = s_hist[lane * 4 + 1];
                    unsigned c2 = s_hist[lane * 4 + 2], c3 = s_hist[lane * 4 + 3];
                    unsigned t3 = c3, t2 = c2 + t3, t1 = c1s + t2, t0 = c0 + t1;
                    unsigned acc = t0;
#pragma unroll
                    for (int d = 1; d < 64; d <<= 1) {
                        unsigned o = __shfl_down(acc, d);
                        if (lane + d < 64) acc += o;
                    }
                    unsigned excl = acc - t0;
                    unsigned Krem = (unsigned)s_refKrem;
                    unsigned incq[4] = { excl + t0, excl + t1, excl + t2, excl + t3 };
                    unsigned abvq[4] = { excl + t1, excl + t2, excl + t3, excl };
#pragma unroll
                    for (int q = 0; q < 4; ++q)
                        if (incq[q] >= Krem && abvq[q] < Krem) s_B2 = lane * 4 + q;
                }
                __syncthreads();
            }
            const int B2 = s_B2;
            for (int j = 0; j < NBOX / BT; ++j) {
                int i = tid + j * BT;
                unsigned k = s_key[i];
                if (k) {
                    int b1, b2; bins_of(k, b1, b2);
                    bool inr = (b1 < U1) || (b1 == U1 && b2 < U2);
                    bool sel = inr && ((b1 > B1) || (b1 == B1 && b2 >= B2));
                    if (sel) {
                        int pos = atomicAdd(&s_cnt, 1);
                        if (pos < CAP)
                            s_sel[pos] = (((u64)k) << 13) | (unsigned)(NBOX - 1 - i);
                    }
                }
            }
            __syncthreads();
            const int sc2 = s_cnt < CAP ? s_cnt : CAP;
            rank_scatter(sc2);
            __syncthreads();
            nms_groups(sc2, false);
            if (s_kc >= MAXDET) break;
            U1 = B1; U2 = B2;
            if (tid < 256) s_hist[tid] = 0u;
            if (tid == 0) s_cnt = 0;
            __syncthreads();
            for (int j = 0; j < NBOX / BT; ++j) {
                unsigned k = s_key[tid + j * BT];
                if (k) {
                    int b1, b2; bins_of(k, b1, b2);
                    if (b1 < U1 || (b1 == U1 && b2 < U2)) atomicAdd(&s_hist[b1], 1u);
                }
            }
        }
        __syncthreads();
    }
    __syncthreads();

    // ---- output: 100 slots ----
    if (tid < MAXDET) {
        const int kc = s_kc;
        float* ob = out;                 // (100,12)
        float* od = out + MAXDET * 12;   // (100,3)
        float* os = out + MAXDET * 15;   // (100,)
        float* ol = out + MAXDET * 16;   // (100,) labels
        float* oo = out + MAXDET * 17;   // (100,) orient
        float4* obr = reinterpret_cast<float4*>(ob + tid * 12);
        if (tid < kc) {
            u64 v = s_kv[tid];
            float sscore = __uint_as_float(((unsigned)(v >> 13)) & 0x7FFFFFFFu);
            int cp = (int)s_kcp[tid];
            obr[0] = s_kb[tid];
            os[tid] = sscore;
            ol[tid] = 0.0f;
            if (cp != 0xFFFF) {
                obr[1] = s_pay[cp][0];
                obr[2] = s_pay[cp][1];
                float4 dd = s_pay[cp][2];
                od[tid * 3 + 0] = dd.x; od[tid * 3 + 1] = dd.y; od[tid * 3 + 2] = dd.z;
                oo[tid] = (float)s_orr[cp];
            } else {
                int idx = NBOX - 1 - (int)(v & 8191ull);
                const float4* br = reinterpret_cast<const float4*>(boxes + idx * 12);
                obr[1] = br[1]; obr[2] = br[2];
                od[tid * 3 + 0] = dims[idx * 3 + 0];
                od[tid * 3 + 1] = dims[idx * 3 + 1];
                od[tid * 3 + 2] = dims[idx * 3 + 2];
                const float4 c0 = *reinterpret_cast<const float4*>(cls + idx * 8);
                const float4 c1 = *reinterpret_cast<const float4*>(cls + idx * 8 + 4);
                float m0 = fmaxf(c0.x, c1.x), m1 = fmaxf(c0.y, c1.y);
                float m2 = fmaxf(c0.z, c1.z), m3 = fmaxf(c0.w, c1.w);
                int o = 0; float best = m0;
                if (m1 > best) { best = m1; o = 1; }
                if (m2 > best) { best = m2; o = 2; }
                if (m3 > best) { best = m3; o = 3; }
                oo[tid] = (float)o;
            }
        } else {
            const float4 neg1 = make_float4(-1.f, -1.f, -1.f, -1.f);
            obr[0] = neg1; obr[1] = neg1; obr[2] = neg1;
            od[tid * 3 + 0] = -1.0f; od[tid * 3 + 1] = -1.0f; od[tid * 3 + 2] = -1.0f;
            os[tid] = -1.0f; ol[tid] = -1.0f; oo[tid] = -1.0f;
        }
    }
}

extern "C" void kernel_launch(void* const* d_in, const int* in_sizes, int n_in,
                              void* d_out, int out_size, void* d_ws, size_t ws_size,
                              hipStream_t stream) {
    const float* boxes = (const float*)d_in[0];
    const float* dims  = (const float*)d_in[1];
    const float* cls   = (const float*)d_in[2];
    float* out = (float*)d_out;
    (void)in_sizes; (void)n_in; (void)out_size; (void)d_ws; (void)ws_size;
    filterdet_kernel<<<1, BT, 0, stream>>>(boxes, dims, cls, out);
}